// Round 4
// baseline (671.522 us; speedup 1.0000x reference)
//
#include <hip/hip_runtime.h>

// MonarchAttentionPerformer MI355X — round 8:
//  * 128x128 path reverted to EXACT round-4 state (628.8 us verified; r7's
//    m204 swizzle on it was a net -2% -> removed).
//  * G1/G5 moved to mgemm8p: 256x256, BK=64, 8 waves, 2-buffer LDS (128 KiB),
//    m201-style phased schedule: 4 phases/K-tile, each {jit ds_read frags ->
//    s_barrier -> setprio+16 MFMA -> s_barrier}; full next-tile stage burst
//    (8 global_load_lds) at phase 0; boundary vmcnt(0) at phase 3 waits on
//    loads issued ~3 phases earlier. launch_bounds(512,2) = 256-VGPR cap
//    (acc 128 + frags 48 + addr ~ 200, no spill). XCD-bijective block swizzle
//    (verified on this geometry in r5: FETCH 252->100 MB).
//
//   G1: x16[t][d] @ WkqvT[c][d]  -> KQ f16 [t][1536], V^T bf16 [n][t], xd atomics
//   G2k: KQ @ w16 -> kpT bf16 [m][t] + ksum atomics
//   G2q: KQ+768 @ w16 -> qp bf16 [t][m] + D atomics
//   G3: V^T @ kpT^T (split-K=4) -> kptv32 partials f32 -> reduce -> kptv bf16
//   G4: qp @ kptv^T / (D+eps) -> Y bf16
//   G5: Y @ WprojT^T + bias -> out fp32

#define NTOK   32768
#define RSQRTM 0.05103103630798288f   // 1/sqrt(384)

typedef _Float16 f16;
typedef f16   f16x8 __attribute__((ext_vector_type(8)));
typedef f16   f16x4 __attribute__((ext_vector_type(4)));
typedef short s16x8 __attribute__((ext_vector_type(8)));
typedef float f32x4 __attribute__((ext_vector_type(4)));

typedef const void __attribute__((address_space(1))) gv_t;
typedef void       __attribute__((address_space(3))) lv_t;
#define GLL16(g, l) __builtin_amdgcn_global_load_lds((gv_t*)(g), (lv_t*)(l), 16, 0, 0)

__device__ __forceinline__ float b2f(unsigned short u){
  union{unsigned int i; float f;} v; v.i = ((unsigned int)u)<<16; return v.f;
}
__device__ __forceinline__ unsigned short f2b(float f){
  union{float f; unsigned int i;} v; v.f = f;
  unsigned int x = v.i;
  x += 0x7fffu + ((x>>16)&1u);
  return (unsigned short)(x>>16);
}

template<typename T> struct MfmaOp;
template<> struct MfmaOp<f16> {
  typedef f16x8 frag;
  static __device__ __forceinline__ f32x4 run(frag a, frag b, f32x4 c){
    return __builtin_amdgcn_mfma_f32_16x16x32_f16(a, b, c, 0, 0, 0);
  }
};
template<> struct MfmaOp<short> {   // bf16 payload
  typedef s16x8 frag;
  static __device__ __forceinline__ f32x4 run(frag a, frag b, f32x4 c){
    return __builtin_amdgcn_mfma_f32_16x16x32_bf16(a, b, c, 0, 0, 0);
  }
};

// ---------------- converters / builders ----------------
__global__ void cvt16(const float4* __restrict__ src, f16* __restrict__ dst, int n4){
  const int i = blockIdx.x*256 + threadIdx.x;
  if (i >= n4) return;
  const float4 v = src[i];
  f16x4 h; h[0]=(f16)v.x; h[1]=(f16)v.y; h[2]=(f16)v.z; h[3]=(f16)v.w;
  *reinterpret_cast<f16x4*>(dst + 4*(long)i) = h;
}
__global__ void build_wkqvT(const float* __restrict__ w1, const float* __restrict__ w2,
                            f16* __restrict__ Wt){
  const int idx = blockIdx.x*256 + threadIdx.x;   // 2304*768
  const int j = idx / 768, i = idx % 768;
  const int k = i / 192, p = i % 192;
  const int s = j >> 2,  l = j & 3;
  float acc = 0.f;
  #pragma unroll 4
  for(int u=0; u<48; ++u)
    acc += w1[(k*192 + l*48+u)*192 + p] * w2[(l*576+s)*192 + 4*u+k];
  Wt[idx] = (f16)acc;
}
__global__ void build_wprojT(const float* __restrict__ w1, const float* __restrict__ w2,
                             unsigned short* __restrict__ Wt){
  const int idx = blockIdx.x*256 + threadIdx.x;   // 768*768
  const int j = idx / 768, i = idx % 768;
  const int k = i / 192, p = i % 192;
  const int s = j >> 2,  l = j & 3;
  float acc = 0.f;
  #pragma unroll 4
  for(int u=0; u<48; ++u)
    acc += w1[(k*192 + l*48+u)*192 + p] * w2[(l*192+s)*192 + 4*u+k];
  Wt[idx] = f2b(acc);
}
// kptv[b][i] = bf16( sum_s kptv32[(b*4+s)][i] )
__global__ void reduce_kptv(const float* __restrict__ p32, unsigned short* __restrict__ o){
  const int idx = blockIdx.x*256 + threadIdx.x;   // 8*294912
  const int b = idx / 294912, i = idx % 294912;
  const float* base = p32 + (long)b*4*294912 + i;
  o[idx] = f2b(base[0] + base[294912] + base[2*294912] + base[3*294912]);
}

// ---------------- MFMA GEMM, BK=64, XOR-swizzled LDS (128x128, round-4) ----
// C[M][N] = A[M][K] * Bt[N][K]^T. 256 thr = 4 waves (2x2), 16x16x32 MFMA.
// EPI: 1 G2k (exp -> kpT transposed; ksum partials -> aux2 atomics)
//      2 G2q (exp -> qp; D partials -> out2 atomics, ksum read from aux2)
//      3 G3  (fp32 partial store, split-K)
//      4 G4  (acc/(D[t]+1e-8) -> bf16, batched)
template<typename T, int BM, int BN, int EPI, int SPLIT>
__global__ __launch_bounds__(256)
void mgemm(const T* __restrict__ A, int lda, long aB,
           const T* __restrict__ Bt, int ldb, long bB,
           int K, void* __restrict__ out, int ldo, long outB,
           void* __restrict__ out2,
           const float* __restrict__ aux, long auxB,
           float* __restrict__ aux2){
  constexpr int MT = BM/32, NT = BN/32;
  constexpr int IA = BM/32, IB = BN/32;   // GLL16 insts per wave per iter
  __shared__ T As[BM*64];
  __shared__ T Bs[BN*64];
  typedef typename MfmaOp<T>::frag frag_t;

  const int tid = threadIdx.x, lane = tid & 63, w = tid >> 6;
  const int wm = w >> 1, wn = w & 1;
  const int ln = lane & 15, q = lane >> 4;
  const int bz = blockIdx.z;
  const int batch = bz / SPLIT;
  const int kstart = (bz % SPLIT) * K;
  const long m0 = (long)blockIdx.y * BM;
  const int  n0 = blockIdx.x * BN;
  const T* Ab = A  + (long)batch*aB;
  const T* Bb = Bt + (long)batch*bB;

  f32x4 acc[MT][NT];
  const f32x4 zero = {0.f, 0.f, 0.f, 0.f};
  #pragma unroll
  for(int i=0;i<MT;i++)
    #pragma unroll
    for(int j=0;j<NT;j++) acc[i][j] = zero;

  for (int k0 = kstart; k0 < kstart + K; k0 += 64){
    __syncthreads();
    #pragma unroll
    for (int i = 0; i < IA; ++i){
      const int e = (w*IA + i)*64 + lane;
      const int m = e >> 3, j = (e & 7) ^ (m & 7);
      GLL16(Ab + (m0 + m)*lda + k0 + j*8, As + (size_t)(w*IA + i)*512);
    }
    #pragma unroll
    for (int i = 0; i < IB; ++i){
      const int e = (w*IB + i)*64 + lane;
      const int n = e >> 3, j = (e & 7) ^ (n & 7);
      GLL16(Bb + (long)(n0 + n)*ldb + k0 + j*8, Bs + (size_t)(w*IB + i)*512);
    }
    __syncthreads();

    #pragma unroll
    for (int kk = 0; kk < 2; ++kk){
      frag_t a[MT], b[NT];
      #pragma unroll
      for (int mt=0; mt<MT; ++mt){
        const int r = wm*MT*16 + mt*16 + ln;
        a[mt] = *reinterpret_cast<const frag_t*>(&As[(r*8 + ((kk*4+q) ^ (r&7)))*8]);
      }
      #pragma unroll
      for (int nt=0; nt<NT; ++nt){
        const int r = wn*NT*16 + nt*16 + ln;
        b[nt] = *reinterpret_cast<const frag_t*>(&Bs[(r*8 + ((kk*4+q) ^ (r&7)))*8]);
      }
      #pragma unroll
      for (int mt=0; mt<MT; ++mt)
        #pragma unroll
        for (int nt=0; nt<NT; ++nt)
          acc[mt][nt] = MfmaOp<T>::run(a[mt], b[nt], acc[mt][nt]);
    }
  }

  // ---- epilogues ----
  if constexpr(EPI==1){               // G2k: kpT + ksum fusion
    const int b = (int)(m0 >> 12);
    float cs[NT];
    #pragma unroll
    for(int nt=0;nt<NT;nt++) cs[nt]=0.f;
    #pragma unroll
    for (int mt=0; mt<MT; ++mt){
      const long mbase = m0 + wm*MT*16 + mt*16 + q*4;
      float xv[4];
      #pragma unroll
      for(int r=0;r<4;r++) xv[r] = aux[mbase + r];
      #pragma unroll
      for (int nt=0; nt<NT; ++nt){
        const int n = n0 + wn*NT*16 + nt*16 + ln;
        const f32x4 c = acc[mt][nt];
        ushort4 v;
        v.x = f2b(__expf(c[0]-xv[0])*RSQRTM);
        v.y = f2b(__expf(c[1]-xv[1])*RSQRTM);
        v.z = f2b(__expf(c[2]-xv[2])*RSQRTM);
        v.w = f2b(__expf(c[3]-xv[3])*RSQRTM);
        *reinterpret_cast<ushort4*>(&((unsigned short*)out)[(long)n*ldo + mbase]) = v;
        cs[nt] += b2f(v.x)+b2f(v.y)+b2f(v.z)+b2f(v.w);
      }
    }
    #pragma unroll
    for (int nt=0; nt<NT; ++nt){
      cs[nt] += __shfl_xor(cs[nt], 16);
      cs[nt] += __shfl_xor(cs[nt], 32);
      if (lane < 16)
        atomicAdd(&aux2[b*384 + n0 + wn*NT*16 + nt*16 + lane], cs[nt]);
    }
    return;
  }

  #pragma unroll
  for (int mt=0; mt<MT; ++mt){
    const long mbase = m0 + wm*MT*16 + mt*16 + q*4;
    if constexpr(EPI==2){             // G2q: qp + D fusion
      const int b = (int)(m0 >> 12);
      float xv[4], dp[4] = {0.f,0.f,0.f,0.f};
      #pragma unroll
      for(int r=0;r<4;r++) xv[r] = aux[mbase + r];
      #pragma unroll
      for (int nt=0; nt<NT; ++nt){
        const int n = n0 + wn*NT*16 + nt*16 + ln;
        const f32x4 c = acc[mt][nt];
        const float ksn = aux2[b*384 + n];
        #pragma unroll
        for(int r=0;r<4;r++){
          const unsigned short h = f2b(__expf(c[r]-xv[r])*RSQRTM);
          ((unsigned short*)out)[(mbase+r)*ldo + n] = h;
          dp[r] += b2f(h)*ksn;
        }
      }
      #pragma unroll
      for(int r=0;r<4;r++){
        #pragma unroll
        for(int mask=1; mask<16; mask<<=1) dp[r] += __shfl_xor(dp[r], mask);
      }
      if (ln == 0){
        #pragma unroll
        for(int r=0;r<4;r++)
          atomicAdd(&((float*)out2)[mbase + r], dp[r]);
      }
    } else if constexpr(EPI==3){      // G3: fp32 partial
      float* o = (float*)out + (long)bz*outB;
      #pragma unroll
      for (int nt=0; nt<NT; ++nt){
        const int n = n0 + wn*NT*16 + nt*16 + ln;
        const f32x4 c = acc[mt][nt];
        #pragma unroll
        for(int r=0;r<4;r++) o[(mbase+r)*ldo + n] = c[r];
      }
    } else if constexpr(EPI==4){      // G4: /(D+eps) -> bf16
      unsigned short* o = (unsigned short*)out + (long)bz*outB;
      float xv[4];
      #pragma unroll
      for(int r=0;r<4;r++) xv[r] = 1.f/(aux[bz*auxB + mbase + r] + 1e-8f);
      #pragma unroll
      for (int nt=0; nt<NT; ++nt){
        const int n = n0 + wn*NT*16 + nt*16 + ln;
        const f32x4 c = acc[mt][nt];
        #pragma unroll
        for(int r=0;r<4;r++) o[(mbase+r)*ldo + n] = f2b(c[r]*xv[r]);
      }
    }
  }
}

// ---------------- 256x256 phased MFMA GEMM (G1/G5) ----------------
// 512 thr = 8 waves (2Mx4N); per-wave C = 128x64 (MT=8, NT=4). BK=64.
// LDS: 2 buffers x (A,B) x 2 M-halves x [128][64] = 128 KiB -> 1 block/CU.
// Schedule per K-tile t (buffer s=t&1): 4 phases, each
//   {jit ds_read frags -> s_barrier -> setprio(1)+16 MFMA+setprio(0) -> s_barrier}
// Phase reads (kk x qm split; 8/4/8/4 ds_read_b128, nothing read twice):
//   P0: a[qm0,kk0]x4 + b[kk0]x4 (+ stage burst of tile t+1: 8 GLL16)
//   P1: a[qm1,kk0]x4          P2: a[qm0,kk1]x4 + b[kk1]x4   P3: a[qm1,kk1]x4
// Boundary vmcnt(0) at P3 waits on loads issued 3 phases (~500+ cy) earlier.
// Ring safety: stage(t+1)->buffer s^1 issued after the barrier that closed all
// reads of s^1's old data (tile t-1, its P3); reads of t+1 only after vmcnt+bar.
// LDS swizzle = round-4's (16B chunk j of row r at slot j^(r&7)): conflict-free
// ds_read_b128 (2-way max), GLL-compatible via inverse-swizzled global source.
// Fragment chunk = (kk*4+q)^(ln&7) — mt/qm-independent (16,64 = 0 mod 8).
// EPI: 0 G1 (KQ f16 + V^T bf16 + bias; xd partials -> aux2 atomics)
//      5 G5 (acc + bias -> fp32)
#define BAR8() asm volatile("s_barrier" ::: "memory")
template<typename T, int EPI, int KTOT>
__global__ __launch_bounds__(512, 2)
void mgemm8p(const T* __restrict__ A, int lda,
             const T* __restrict__ Bt, int ldb,
             void* __restrict__ out, int ldo,
             void* __restrict__ out2,
             const float* __restrict__ aux,
             float* __restrict__ aux2){
  constexpr int NTIL = KTOT / 64;
  __shared__ T As[2][2][8192];     // [buf][m-half][128*64]
  __shared__ T Bs[2][2][8192];     // [buf][n-half][128*64]
  typedef typename MfmaOp<T>::frag frag_t;

  const int tid = threadIdx.x, lane = tid & 63, w = tid >> 6;
  const int wm = w >> 2, wn = w & 3;
  const int ln = lane & 15, q = lane >> 4;

  // bijective XCD-aware block swizzle (nwg % 8 == 0 at both call sites)
  const int gx = gridDim.x;
  const int nwg = gx * (int)gridDim.y;
  int bid = blockIdx.y * gx + blockIdx.x;
  bid = (bid & 7) * (nwg >> 3) + (bid >> 3);
  const int  n0 = (bid % gx) * 256;
  const long m0 = (long)(bid / gx) * 256;

  // staging sources (inverse-swizzled): dest chunk e holds col-chunk (e&7)^(r&7)
  const T* aSrc[2]; const T* bSrc[2]; int dOff[2];
  #pragma unroll
  for (int j = 0; j < 2; ++j){
    const int e = j*512 + tid;
    const int r = e >> 3, c = (e & 7) ^ (r & 7);
    aSrc[j] = A  + (m0 + r)*lda + c*8;
    bSrc[j] = Bt + (long)(n0 + r)*ldb + c*8;
    dOff[j] = (j*512 + w*64) * 8;     // elements; +lane*16B implicit
  }

#define STAGE_TILE(tt)                                                       \
  if ((tt) < NTIL){                                                          \
    const int sb_ = (tt) & 1; const long ko_ = (long)(tt) * 64;              \
    _Pragma("unroll")                                                        \
    for (int j = 0; j < 2; ++j){                                             \
      GLL16(aSrc[j] + ko_,                 &As[sb_][0][0] + dOff[j]);        \
      GLL16(aSrc[j] + 128*lda + ko_,       &As[sb_][1][0] + dOff[j]);        \
      GLL16(bSrc[j] + ko_,                 &Bs[sb_][0][0] + dOff[j]);        \
      GLL16(bSrc[j] + (long)128*ldb + ko_, &Bs[sb_][1][0] + dOff[j]);        \
    }                                                                        \
  }

#define MM16(mb, av, bv)                                                     \
  __builtin_amdgcn_s_setprio(1);                                             \
  _Pragma("unroll")                                                          \
  for (int mt = 0; mt < 4; ++mt)                                             \
    _Pragma("unroll")                                                        \
    for (int nt = 0; nt < 4; ++nt)                                           \
      acc[(mb)+mt][nt] = MfmaOp<T>::run(av[mt], bv[nt], acc[(mb)+mt][nt]);   \
  __builtin_amdgcn_s_setprio(0);

  const int arow = ln * 64;                       // A within-half row base (elems)
  const int brow = (wn & 1) * 4096 + ln * 64;     // B within-half row base
  const int cx0  = ( q      ^ (ln & 7)) * 8;      // kk=0 swizzled chunk offset
  const int cx1  = ((4 + q) ^ (ln & 7)) * 8;      // kk=1

  f32x4 acc[8][4];
  const f32x4 zero = {0.f,0.f,0.f,0.f};
  #pragma unroll
  for (int m=0;m<8;m++)
    #pragma unroll
    for (int n=0;n<4;n++) acc[m][n] = zero;

  // prologue: stage tile 0, drain once, sync
  STAGE_TILE(0);
  asm volatile("s_waitcnt vmcnt(0)" ::: "memory");
  BAR8();

  for (int t = 0; t < NTIL; ++t){
    const int s = t & 1;
    const T* Ah = &As[s][wm][0];
    const T* Bh = &Bs[s][wn >> 1][0];
    frag_t a0[4], a1[4], b0[4];

    // ---- P0: a[qm0,kk0] + b[kk0]; stage burst for tile t+1 ----
    #pragma unroll
    for (int mt=0; mt<4; ++mt)
      a0[mt] = *reinterpret_cast<const frag_t*>(Ah + mt*1024 + arow + cx0);
    #pragma unroll
    for (int nt=0; nt<4; ++nt)
      b0[nt] = *reinterpret_cast<const frag_t*>(Bh + nt*1024 + brow + cx0);
    STAGE_TILE(t+1);
    BAR8();
    MM16(0, a0, b0);
    BAR8();

    // ---- P1: a[qm1,kk0] ----
    #pragma unroll
    for (int mt=0; mt<4; ++mt)
      a1[mt] = *reinterpret_cast<const frag_t*>(Ah + 4096 + mt*1024 + arow + cx0);
    BAR8();
    MM16(4, a1, b0);
    BAR8();

    // ---- P2: a[qm0,kk1] + b[kk1] ----
    #pragma unroll
    for (int mt=0; mt<4; ++mt)
      a0[mt] = *reinterpret_cast<const frag_t*>(Ah + mt*1024 + arow + cx1);
    #pragma unroll
    for (int nt=0; nt<4; ++nt)
      b0[nt] = *reinterpret_cast<const frag_t*>(Bh + nt*1024 + brow + cx1);
    BAR8();
    MM16(0, a0, b0);
    BAR8();

    // ---- P3: a[qm1,kk1]; boundary wait ----
    #pragma unroll
    for (int mt=0; mt<4; ++mt)
      a1[mt] = *reinterpret_cast<const frag_t*>(Ah + 4096 + mt*1024 + arow + cx1);
    BAR8();
    MM16(4, a1, b0);
    asm volatile("s_waitcnt vmcnt(0)" ::: "memory");
    BAR8();
  }

  // ---- epilogues ----
  if constexpr(EPI==0){               // G1: KQ/V + bias + xd fusion
    const int nw = n0 + wn*64;
    const int part = nw / 768;        // 0=K, 1=Q, 2=V (wave-uniform: 64 | 768)
    #pragma unroll
    for (int mt=0; mt<8; ++mt){
      const long mbase = m0 + wm*128 + mt*16 + q*4;
      float p[4] = {0.f,0.f,0.f,0.f};
      #pragma unroll
      for (int nt=0; nt<4; ++nt){
        const int n = nw + nt*16 + ln;
        const f32x4 c = acc[mt][nt];
        const float bv = aux[n];
        if (part < 2){
          f16* KQ = (f16*)out;
          #pragma unroll
          for(int r=0;r<4;r++){
            const f16 h = (f16)(c[r] + bv);
            KQ[(mbase+r)*ldo + n] = h;
            const float hf = (float)h;
            p[r] += hf*hf;
          }
        } else {
          unsigned short* VT = (unsigned short*)out2;
          ushort4 v;
          v.x = f2b(c[0]+bv); v.y = f2b(c[1]+bv); v.z = f2b(c[2]+bv); v.w = f2b(c[3]+bv);
          *reinterpret_cast<ushort4*>(&VT[(long)(n-1536)*32768 + mbase]) = v;
        }
      }
      if (part < 2){
        #pragma unroll
        for(int r=0;r<4;r++){
          #pragma unroll
          for(int mask=1; mask<16; mask<<=1) p[r] += __shfl_xor(p[r], mask);
        }
        if (ln == 0){
          #pragma unroll
          for(int r=0;r<4;r++)
            atomicAdd(&aux2[part*NTOK + mbase + r], 0.5f*p[r]);
        }
      }
    }
  } else {                            // EPI==5: G5, +bias -> fp32
    float* o = (float*)out;
    #pragma unroll
    for (int mt=0; mt<8; ++mt){
      const long mbase = m0 + wm*128 + mt*16 + q*4;
      #pragma unroll
      for (int nt=0; nt<4; ++nt){
        const int n = n0 + wn*64 + nt*16 + ln;
        const f32x4 c = acc[mt][nt];
        const float bv = aux[n];
        #pragma unroll
        for(int r=0;r<4;r++) o[(mbase+r)*ldo + n] = c[r] + bv;
      }
    }
  }
  (void)out2; (void)aux2;
#undef STAGE_TILE
#undef MM16
}

// ---------------- launcher ----------------
extern "C" void kernel_launch(void* const* d_in, const int* in_sizes, int n_in,
                              void* d_out, int out_size, void* d_ws, size_t ws_size,
                              hipStream_t stream){
  (void)in_sizes; (void)n_in; (void)out_size;
  const float* x       = (const float*)d_in[0];
  const float* kqv_w1  = (const float*)d_in[1];
  const float* kqv_w2  = (const float*)d_in[2];
  const float* kqv_b   = (const float*)d_in[3];
  const float* proj_w1 = (const float*)d_in[4];
  const float* proj_w2 = (const float*)d_in[5];
  const float* proj_b  = (const float*)d_in[6];
  const float* w       = (const float*)d_in[7];
  char* ws = (char*)d_ws;

  const size_t o_WkqvT  = 0;          // 2304*768 f16   =   3,538,944
  const size_t o_WprojT = 3538944;    // 768*768 bf16   =   1,179,648
  const size_t o_w16    = 4718592;    // 384*768 f16    =     589,824
  const size_t o_x16    = 5308416;    // 32768*768 f16  =  50,331,648
  const size_t o_KQ     = 55640064;   // 32768*1536 f16 = 100,663,296
  const size_t o_VT     = 156303360;  // 768*32768 bf16 =  50,331,648
  const size_t o_xd     = 206635008;  // 2*32768 f32    =     262,144 ┐
  const size_t o_ksum   = 206897152;  // 3072 f32       =      12,288 │ zero block
  const size_t o_Dv     = 206909440;  // 32768 f32      =     131,072 ┘
  const size_t o_kpT    = 207040512;  // 384*32768 bf16 =  25,165,824
  const size_t o_qp     = 232206336;  // 32768*384 bf16 =  25,165,824
  const size_t o_kptv32 = 257372160;  // 32*294912 f32  =  37,748,736
  const size_t o_kptv   = 295120896;  // 8*294912 bf16  =   4,718,592
  const size_t o_Y      = 299839488;  // 32768*768 bf16 =  50,331,648
  const size_t TOTAL    = 350171136;
  if (ws_size < TOTAL) return;

  f16*            WkqvT  = (f16*)(ws + o_WkqvT);
  short*          WprojT = (short*)(ws + o_WprojT);
  f16*            w16    = (f16*)(ws + o_w16);
  f16*            x16    = (f16*)(ws + o_x16);
  f16*            KQ     = (f16*)(ws + o_KQ);
  short*          VT     = (short*)(ws + o_VT);
  float*          xd     = (float*)(ws + o_xd);
  float*          ksum   = (float*)(ws + o_ksum);
  float*          Dv     = (float*)(ws + o_Dv);
  short*          kpT    = (short*)(ws + o_kpT);
  short*          qp     = (short*)(ws + o_qp);
  float*          kptv32 = (float*)(ws + o_kptv32);
  unsigned short* kptv   = (unsigned short*)(ws + o_kptv);
  short*          Y      = (short*)(ws + o_Y);

  hipMemsetAsync(ws + o_xd, 0, 405504, stream);   // xd + ksum + Dv

  cvt16<<<24576, 256, 0, stream>>>((const float4*)x, x16, 6291456);
  cvt16<<<288,   256, 0, stream>>>((const float4*)w, w16, 73728);
  build_wkqvT <<<6912, 256, 0, stream>>>(kqv_w1, kqv_w2, WkqvT);
  build_wprojT<<<2304, 256, 0, stream>>>(proj_w1, proj_w2, (unsigned short*)WprojT);

  // G1: [32768 x 2304 x 768] f16 (+ xd fusion) — phased 256² path
  mgemm8p<f16, 0, 768><<<dim3(9,128,1), 512, 0, stream>>>(
      x16, 768, WkqvT, 768, KQ, 1536, VT, kqv_b, xd);

  // G2k: [32768 x 384 x 768] -> kpT (+ ksum fusion)
  mgemm<f16,128,128,1,1><<<dim3(3,256,1), 256, 0, stream>>>(
      KQ, 1536, 0L, w16, 768, 0L, 768, kpT, 32768, 0L, nullptr, xd, 0L, ksum);

  // G2q: [32768 x 384 x 768] -> qp (+ D fusion; reads ksum)
  mgemm<f16,128,128,2,1><<<dim3(3,256,1), 256, 0, stream>>>(
      KQ + 768, 1536, 0L, w16, 768, 0L, 768, qp, 384, 0L, Dv, xd + NTOK, 0L, ksum);

  // G3: kptv32[b*4+s] partial = V^T[b] @ kpT[b]^T over K-chunk s  (split-K=4)
  mgemm<short,128,128,3,4><<<dim3(3,6,32), 256, 0, stream>>>(
      VT, 32768, 4096L, kpT, 32768, 4096L, 1024, kptv32, 384, 294912L,
      nullptr, nullptr, 0L, nullptr);
  reduce_kptv<<<9216, 256, 0, stream>>>(kptv32, kptv);

  // G4: Y = (qp @ kptv^T)/(D+eps)  [4096 x 768 x 384] x8
  mgemm<short,128,128,4,1><<<dim3(6,32,8), 256, 0, stream>>>(
      qp, 384, 1572864L, (short*)kptv, 384, 294912L, 384, Y, 768, 3145728L,
      nullptr, Dv, 4096L, nullptr);

  // G5: out = Y @ WprojT^T + bias  [32768 x 768 x 768] -> fp32 — phased path
  mgemm8p<short, 5, 768><<<dim3(3,128,1), 512, 0, stream>>>(
      Y, 768, WprojT, 768, d_out, 768, nullptr, proj_b, nullptr);
}

// Round 5
// 613.892 us; speedup vs baseline: 1.0939x; 1.0939x over previous
//
#include <hip/hip_runtime.h>

// MonarchAttentionPerformer MI355X — round 9: G5 eliminated by algebra.
//   diag(1/D)·(qp·kptv^T)·Wp^T + b  ==  diag(1/D)·qp·(Wp·kptv)^T + b
// so:  Gz: Z[b] = WprojT · kptvT[b]^T   (tiny per-batch GEMM 768x384x768)
//      G45: out = (qp·Z^T)/(D+eps) + bias   (G4's geometry, fp32 epilogue)
// G5 (3.9e10 FLOP, ~60us) and the Y buffer (100 MB traffic) are gone.
// reduce_kptv -> reduce_kptv_t (64x64 LDS transpose, coalesced both sides)
// so kptv^T [m][n] can be the Bt operand of Gz.
// G1/G2k/G2q/G3 are EXACT round-4 state (verified 628.8 us; r5-r8 structural
// experiments on G1 all regressed and are retired).
//
//   G1: x16[t][d] @ WkqvT[c][d]  -> KQ f16 [t][1536], V^T bf16 [n][t], xd atomics
//   G2k: KQ @ w16 -> kpT bf16 [m][t] + ksum atomics
//   G2q: KQ+768 @ w16 -> qp bf16 [t][m] + D atomics
//   G3: V^T @ kpT^T (split-K=4) -> kptv32 partials f32 [s][n][m]
//   reduce_kptv_t: sum 4 partials -> kptvT bf16 [b][m][n]
//   Gz: WprojT @ kptvT^T -> Z bf16 [b][j][m]
//   G45: (qp @ Z^T)/(D+eps) + bias -> out fp32

#define NTOK   32768
#define RSQRTM 0.05103103630798288f   // 1/sqrt(384)

typedef _Float16 f16;
typedef f16   f16x8 __attribute__((ext_vector_type(8)));
typedef f16   f16x4 __attribute__((ext_vector_type(4)));
typedef short s16x8 __attribute__((ext_vector_type(8)));
typedef float f32x4 __attribute__((ext_vector_type(4)));

typedef const void __attribute__((address_space(1))) gv_t;
typedef void       __attribute__((address_space(3))) lv_t;
#define GLL16(g, l) __builtin_amdgcn_global_load_lds((gv_t*)(g), (lv_t*)(l), 16, 0, 0)

__device__ __forceinline__ float b2f(unsigned short u){
  union{unsigned int i; float f;} v; v.i = ((unsigned int)u)<<16; return v.f;
}
__device__ __forceinline__ unsigned short f2b(float f){
  union{float f; unsigned int i;} v; v.f = f;
  unsigned int x = v.i;
  x += 0x7fffu + ((x>>16)&1u);
  return (unsigned short)(x>>16);
}

template<typename T> struct MfmaOp;
template<> struct MfmaOp<f16> {
  typedef f16x8 frag;
  static __device__ __forceinline__ f32x4 run(frag a, frag b, f32x4 c){
    return __builtin_amdgcn_mfma_f32_16x16x32_f16(a, b, c, 0, 0, 0);
  }
};
template<> struct MfmaOp<short> {   // bf16 payload
  typedef s16x8 frag;
  static __device__ __forceinline__ f32x4 run(frag a, frag b, f32x4 c){
    return __builtin_amdgcn_mfma_f32_16x16x32_bf16(a, b, c, 0, 0, 0);
  }
};

// ---------------- converters / builders ----------------
__global__ void cvt16(const float4* __restrict__ src, f16* __restrict__ dst, int n4){
  const int i = blockIdx.x*256 + threadIdx.x;
  if (i >= n4) return;
  const float4 v = src[i];
  f16x4 h; h[0]=(f16)v.x; h[1]=(f16)v.y; h[2]=(f16)v.z; h[3]=(f16)v.w;
  *reinterpret_cast<f16x4*>(dst + 4*(long)i) = h;
}
__global__ void build_wkqvT(const float* __restrict__ w1, const float* __restrict__ w2,
                            f16* __restrict__ Wt){
  const int idx = blockIdx.x*256 + threadIdx.x;   // 2304*768
  const int j = idx / 768, i = idx % 768;
  const int k = i / 192, p = i % 192;
  const int s = j >> 2,  l = j & 3;
  float acc = 0.f;
  #pragma unroll 4
  for(int u=0; u<48; ++u)
    acc += w1[(k*192 + l*48+u)*192 + p] * w2[(l*576+s)*192 + 4*u+k];
  Wt[idx] = (f16)acc;
}
__global__ void build_wprojT(const float* __restrict__ w1, const float* __restrict__ w2,
                             unsigned short* __restrict__ Wt){
  const int idx = blockIdx.x*256 + threadIdx.x;   // 768*768
  const int j = idx / 768, i = idx % 768;
  const int k = i / 192, p = i % 192;
  const int s = j >> 2,  l = j & 3;
  float acc = 0.f;
  #pragma unroll 4
  for(int u=0; u<48; ++u)
    acc += w1[(k*192 + l*48+u)*192 + p] * w2[(l*192+s)*192 + 4*u+k];
  Wt[idx] = f2b(acc);
}
// kptvT[b][m][n] = bf16( sum_s kptv32[(b*4+s)][n][m] )  — 64x64 LDS transpose
__global__ void reduce_kptv_t(const float* __restrict__ p32, unsigned short* __restrict__ o){
  __shared__ float t[64][65];
  const int b = blockIdx.z, n0 = blockIdx.x*64, m0 = blockIdx.y*64;
  const int tx = threadIdx.x & 63, ty = threadIdx.x >> 6;
  const float* base = p32 + (long)b*4*294912;
  #pragma unroll 4
  for (int r = 0; r < 16; ++r){
    const int n = n0 + ty*16 + r;
    const int idx = n*384 + m0 + tx;
    t[tx][ty*16+r] = base[idx] + base[294912+idx] + base[2*294912+idx] + base[3*294912+idx];
  }
  __syncthreads();
  unsigned short* ob = o + (long)b*294912;
  #pragma unroll 4
  for (int r = 0; r < 16; ++r){
    const int m = m0 + ty*16 + r;
    ob[(long)m*768 + n0 + tx] = f2b(t[ty*16+r][tx]);
  }
}

// ---------------- MFMA GEMM, BK=64, XOR-swizzled LDS ----------------
// C[M][N] = A[M][K] * Bt[N][K]^T. 256 thr = 4 waves (2x2), 16x16x32 MFMA.
// LDS: row-major chunks of 8 elems; chunk j of row m stored at slot j^(m&7).
// EPI: 0 G1  (KQ f16 + V^T bf16 + bias; xd partials -> aux2 atomics)
//      1 G2k (exp -> kpT transposed; ksum partials -> aux2 atomics)
//      2 G2q (exp -> qp; D partials -> out2 atomics, ksum read from aux2)
//      3 G3  (fp32 partial store, split-K)
//      6 Gz  (bf16 store, batched)
//      7 G45 (acc/(D[t]+eps) + bias -> fp32, batched)
template<typename T, int BM, int BN, int EPI, int SPLIT>
__global__ __launch_bounds__(256)
void mgemm(const T* __restrict__ A, int lda, long aB,
           const T* __restrict__ Bt, int ldb, long bB,
           int K, void* __restrict__ out, int ldo, long outB,
           void* __restrict__ out2,
           const float* __restrict__ aux, long auxB,
           float* __restrict__ aux2){
  constexpr int MT = BM/32, NT = BN/32;
  constexpr int IA = BM/32, IB = BN/32;   // GLL16 insts per wave per iter
  __shared__ T As[BM*64];
  __shared__ T Bs[BN*64];
  typedef typename MfmaOp<T>::frag frag_t;

  const int tid = threadIdx.x, lane = tid & 63, w = tid >> 6;
  const int wm = w >> 1, wn = w & 1;
  const int ln = lane & 15, q = lane >> 4;
  const int bz = blockIdx.z;
  const int batch = bz / SPLIT;
  const int kstart = (bz % SPLIT) * K;
  const long m0 = (long)blockIdx.y * BM;
  const int  n0 = blockIdx.x * BN;
  const T* Ab = A  + (long)batch*aB;
  const T* Bb = Bt + (long)batch*bB;

  f32x4 acc[MT][NT];
  const f32x4 zero = {0.f, 0.f, 0.f, 0.f};
  #pragma unroll
  for(int i=0;i<MT;i++)
    #pragma unroll
    for(int j=0;j<NT;j++) acc[i][j] = zero;

  for (int k0 = kstart; k0 < kstart + K; k0 += 64){
    __syncthreads();
    #pragma unroll
    for (int i = 0; i < IA; ++i){
      const int e = (w*IA + i)*64 + lane;
      const int m = e >> 3, j = (e & 7) ^ (m & 7);
      GLL16(Ab + (m0 + m)*lda + k0 + j*8, As + (size_t)(w*IA + i)*512);
    }
    #pragma unroll
    for (int i = 0; i < IB; ++i){
      const int e = (w*IB + i)*64 + lane;
      const int n = e >> 3, j = (e & 7) ^ (n & 7);
      GLL16(Bb + (long)(n0 + n)*ldb + k0 + j*8, Bs + (size_t)(w*IB + i)*512);
    }
    __syncthreads();

    #pragma unroll
    for (int kk = 0; kk < 2; ++kk){
      frag_t a[MT], b[NT];
      #pragma unroll
      for (int mt=0; mt<MT; ++mt){
        const int r = wm*MT*16 + mt*16 + ln;
        a[mt] = *reinterpret_cast<const frag_t*>(&As[(r*8 + ((kk*4+q) ^ (r&7)))*8]);
      }
      #pragma unroll
      for (int nt=0; nt<NT; ++nt){
        const int r = wn*NT*16 + nt*16 + ln;
        b[nt] = *reinterpret_cast<const frag_t*>(&Bs[(r*8 + ((kk*4+q) ^ (r&7)))*8]);
      }
      #pragma unroll
      for (int mt=0; mt<MT; ++mt)
        #pragma unroll
        for (int nt=0; nt<NT; ++nt)
          acc[mt][nt] = MfmaOp<T>::run(a[mt], b[nt], acc[mt][nt]);
    }
  }

  // ---- epilogues ----
  if constexpr(EPI==1){               // G2k: kpT + ksum fusion
    const int b = (int)(m0 >> 12);
    float cs[NT];
    #pragma unroll
    for(int nt=0;nt<NT;nt++) cs[nt]=0.f;
    #pragma unroll
    for (int mt=0; mt<MT; ++mt){
      const long mbase = m0 + wm*MT*16 + mt*16 + q*4;
      float xv[4];
      #pragma unroll
      for(int r=0;r<4;r++) xv[r] = aux[mbase + r];
      #pragma unroll
      for (int nt=0; nt<NT; ++nt){
        const int n = n0 + wn*NT*16 + nt*16 + ln;
        const f32x4 c = acc[mt][nt];
        ushort4 v;
        v.x = f2b(__expf(c[0]-xv[0])*RSQRTM);
        v.y = f2b(__expf(c[1]-xv[1])*RSQRTM);
        v.z = f2b(__expf(c[2]-xv[2])*RSQRTM);
        v.w = f2b(__expf(c[3]-xv[3])*RSQRTM);
        *reinterpret_cast<ushort4*>(&((unsigned short*)out)[(long)n*ldo + mbase]) = v;
        cs[nt] += b2f(v.x)+b2f(v.y)+b2f(v.z)+b2f(v.w);
      }
    }
    #pragma unroll
    for (int nt=0; nt<NT; ++nt){
      cs[nt] += __shfl_xor(cs[nt], 16);
      cs[nt] += __shfl_xor(cs[nt], 32);
      if (lane < 16)
        atomicAdd(&aux2[b*384 + n0 + wn*NT*16 + nt*16 + lane], cs[nt]);
    }
    return;
  }

  #pragma unroll
  for (int mt=0; mt<MT; ++mt){
    const long mbase = m0 + wm*MT*16 + mt*16 + q*4;
    if constexpr(EPI==0){             // G1: KQ/V + bias + xd fusion
      const int nw = n0 + wn*NT*16;
      const int part = nw / 768;      // 0=K, 1=Q, 2=V (wave-uniform)
      float p[4] = {0.f,0.f,0.f,0.f};
      #pragma unroll
      for (int nt=0; nt<NT; ++nt){
        const int n = nw + nt*16 + ln;
        const f32x4 c = acc[mt][nt];
        const float bv = aux[n];
        if (part < 2){
          f16* KQ = (f16*)out;
          #pragma unroll
          for(int r=0;r<4;r++){
            const f16 h = (f16)(c[r] + bv);
            KQ[(mbase+r)*1536 + n] = h;
            const float hf = (float)h;
            p[r] += hf*hf;
          }
        } else {
          unsigned short* VT = (unsigned short*)out2;
          ushort4 v;
          v.x = f2b(c[0]+bv); v.y = f2b(c[1]+bv); v.z = f2b(c[2]+bv); v.w = f2b(c[3]+bv);
          *reinterpret_cast<ushort4*>(&VT[(long)(n-1536)*32768 + mbase]) = v;
        }
      }
      if (part < 2){
        #pragma unroll
        for(int r=0;r<4;r++){
          #pragma unroll
          for(int mask=1; mask<16; mask<<=1) p[r] += __shfl_xor(p[r], mask);
        }
        if (ln == 0){
          #pragma unroll
          for(int r=0;r<4;r++)
            atomicAdd(&aux2[part*NTOK + mbase + r], 0.5f*p[r]);
        }
      }
    } else if constexpr(EPI==2){      // G2q: qp + D fusion
      const int b = (int)(m0 >> 12);
      float xv[4], dp[4] = {0.f,0.f,0.f,0.f};
      #pragma unroll
      for(int r=0;r<4;r++) xv[r] = aux[mbase + r];
      #pragma unroll
      for (int nt=0; nt<NT; ++nt){
        const int n = n0 + wn*NT*16 + nt*16 + ln;
        const f32x4 c = acc[mt][nt];
        const float ksn = aux2[b*384 + n];
        #pragma unroll
        for(int r=0;r<4;r++){
          const unsigned short h = f2b(__expf(c[r]-xv[r])*RSQRTM);
          ((unsigned short*)out)[(mbase+r)*ldo + n] = h;
          dp[r] += b2f(h)*ksn;
        }
      }
      #pragma unroll
      for(int r=0;r<4;r++){
        #pragma unroll
        for(int mask=1; mask<16; mask<<=1) dp[r] += __shfl_xor(dp[r], mask);
      }
      if (ln == 0){
        #pragma unroll
        for(int r=0;r<4;r++)
          atomicAdd(&((float*)out2)[mbase + r], dp[r]);
      }
    } else if constexpr(EPI==3){      // G3: fp32 partial
      float* o = (float*)out + (long)bz*outB;
      #pragma unroll
      for (int nt=0; nt<NT; ++nt){
        const int n = n0 + wn*NT*16 + nt*16 + ln;
        const f32x4 c = acc[mt][nt];
        #pragma unroll
        for(int r=0;r<4;r++) o[(mbase+r)*ldo + n] = c[r];
      }
    } else if constexpr(EPI==6){      // Gz: bf16 store, batched
      unsigned short* o = (unsigned short*)out + (long)bz*outB;
      #pragma unroll
      for (int nt=0; nt<NT; ++nt){
        const int n = n0 + wn*NT*16 + nt*16 + ln;
        const f32x4 c = acc[mt][nt];
        #pragma unroll
        for(int r=0;r<4;r++) o[(mbase+r)*ldo + n] = f2b(c[r]);
      }
    } else if constexpr(EPI==7){      // G45: /(D+eps) + bias -> fp32, batched
      float* o = (float*)out + (long)bz*outB;
      float xv[4];
      #pragma unroll
      for(int r=0;r<4;r++) xv[r] = 1.f/(aux[bz*auxB + mbase + r] + 1e-8f);
      #pragma unroll
      for (int nt=0; nt<NT; ++nt){
        const int n = n0 + wn*NT*16 + nt*16 + ln;
        const f32x4 c = acc[mt][nt];
        const float bv = aux2[n];
        #pragma unroll
        for(int r=0;r<4;r++) o[(mbase+r)*ldo + n] = c[r]*xv[r] + bv;
      }
    }
  }
}

// ---------------- launcher ----------------
extern "C" void kernel_launch(void* const* d_in, const int* in_sizes, int n_in,
                              void* d_out, int out_size, void* d_ws, size_t ws_size,
                              hipStream_t stream){
  (void)in_sizes; (void)n_in; (void)out_size;
  const float* x       = (const float*)d_in[0];
  const float* kqv_w1  = (const float*)d_in[1];
  const float* kqv_w2  = (const float*)d_in[2];
  const float* kqv_b   = (const float*)d_in[3];
  const float* proj_w1 = (const float*)d_in[4];
  const float* proj_w2 = (const float*)d_in[5];
  const float* proj_b  = (const float*)d_in[6];
  const float* w       = (const float*)d_in[7];
  char* ws = (char*)d_ws;

  const size_t o_WkqvT  = 0;          // 2304*768 f16   =   3,538,944
  const size_t o_WprojT = 3538944;    // 768*768 bf16   =   1,179,648
  const size_t o_w16    = 4718592;    // 384*768 f16    =     589,824
  const size_t o_x16    = 5308416;    // 32768*768 f16  =  50,331,648
  const size_t o_KQ     = 55640064;   // 32768*1536 f16 = 100,663,296
  const size_t o_VT     = 156303360;  // 768*32768 bf16 =  50,331,648
  const size_t o_xd     = 206635008;  // 2*32768 f32    =     262,144 ┐
  const size_t o_ksum   = 206897152;  // 3072 f32       =      12,288 │ zero block
  const size_t o_Dv     = 206909440;  // 32768 f32      =     131,072 ┘
  const size_t o_kpT    = 207040512;  // 384*32768 bf16 =  25,165,824
  const size_t o_qp     = 232206336;  // 32768*384 bf16 =  25,165,824
  const size_t o_kptv32 = 257372160;  // 32*294912 f32  =  37,748,736
  const size_t o_kptvT  = 295120896;  // 8*294912 bf16  =   4,718,592
  const size_t o_Z      = 299839488;  // 8*294912 bf16  =   4,718,592
  const size_t TOTAL    = 304558080;
  if (ws_size < TOTAL) return;

  f16*            WkqvT  = (f16*)(ws + o_WkqvT);
  short*          WprojT = (short*)(ws + o_WprojT);
  f16*            w16    = (f16*)(ws + o_w16);
  f16*            x16    = (f16*)(ws + o_x16);
  f16*            KQ     = (f16*)(ws + o_KQ);
  short*          VT     = (short*)(ws + o_VT);
  float*          xd     = (float*)(ws + o_xd);
  float*          ksum   = (float*)(ws + o_ksum);
  float*          Dv     = (float*)(ws + o_Dv);
  short*          kpT    = (short*)(ws + o_kpT);
  short*          qp     = (short*)(ws + o_qp);
  float*          kptv32 = (float*)(ws + o_kptv32);
  unsigned short* kptvT  = (unsigned short*)(ws + o_kptvT);
  short*          Z      = (short*)(ws + o_Z);

  hipMemsetAsync(ws + o_xd, 0, 405504, stream);   // xd + ksum + Dv

  cvt16<<<24576, 256, 0, stream>>>((const float4*)x, x16, 6291456);
  cvt16<<<288,   256, 0, stream>>>((const float4*)w, w16, 73728);
  build_wkqvT <<<6912, 256, 0, stream>>>(kqv_w1, kqv_w2, WkqvT);
  build_wprojT<<<2304, 256, 0, stream>>>(proj_w1, proj_w2, (unsigned short*)WprojT);

  // G1: [32768 x 2304 x 768] f16 (+ xd fusion)
  mgemm<f16,128,128,0,1><<<dim3(18,256,1), 256, 0, stream>>>(
      x16, 768, 0L, WkqvT, 768, 0L, 768, KQ, 1536, 0L, VT, kqv_b, 0L, xd);

  // G2k: [32768 x 384 x 768] -> kpT (+ ksum fusion)
  mgemm<f16,128,128,1,1><<<dim3(3,256,1), 256, 0, stream>>>(
      KQ, 1536, 0L, w16, 768, 0L, 768, kpT, 32768, 0L, nullptr, xd, 0L, ksum);

  // G2q: [32768 x 384 x 768] -> qp (+ D fusion; reads ksum)
  mgemm<f16,128,128,2,1><<<dim3(3,256,1), 256, 0, stream>>>(
      KQ + 768, 1536, 0L, w16, 768, 0L, 768, qp, 384, 0L, Dv, xd + NTOK, 0L, ksum);

  // G3: kptv32[b*4+s][n][m] partial = V^T[b] @ kpT[b]^T over K-chunk s (split-K=4)
  mgemm<short,128,128,3,4><<<dim3(3,6,32), 256, 0, stream>>>(
      VT, 32768, 4096L, kpT, 32768, 4096L, 1024, kptv32, 384, 294912L,
      nullptr, nullptr, 0L, nullptr);

  // reduce + transpose: kptvT[b][m][n] bf16
  reduce_kptv_t<<<dim3(12,6,8), 256, 0, stream>>>(kptv32, kptvT);

  // Gz: Z[b][j][m] = sum_n WprojT[j][n] * kptvT[b][m][n]   [768 x 384 x 768] x8
  mgemm<short,128,128,6,1><<<dim3(3,6,8), 256, 0, stream>>>(
      WprojT, 768, 0L, (short*)kptvT, 768, 294912L, 768, Z, 384, 294912L,
      nullptr, nullptr, 0L, nullptr);

  // G45: out[t][j] = (qp[t] . Z[b][j]) / (D[t]+eps) + bias[j]   [4096 x 768 x 384] x8
  mgemm<short,128,128,7,1><<<dim3(6,32,8), 256, 0, stream>>>(
      qp, 384, 1572864L, Z, 384, 294912L, 384, d_out, 768, 3145728L,
      nullptr, Dv, 4096L, (float*)proj_b);
}